// Round 1
// baseline (94.845 us; speedup 1.0000x reference)
//
#include <hip/hip_runtime.h>
#include <math.h>

// StructLoss: sqrt(mean(|grads4(outputs - labels)|) + 1e-16)
// grads4 = 4 directional shift-differences (zero 'same' padding).
// Shapes: [B=16, C=6, H=512, W=512] fp32. mean over B*4C*H*W elements.

#define NBLOCKS 2048
#define NTHREADS 256

__device__ __forceinline__ float4 ld4(const float* p) {
    return *reinterpret_cast<const float4*>(p);
}

__global__ __launch_bounds__(NTHREADS) void struct_loss_partial(
        const float* __restrict__ out_p, const float* __restrict__ lab_p,
        float* __restrict__ partial, int ngroups) {
    constexpr int W = 512, H = 512;
    float acc = 0.f;

    for (int g = blockIdx.x * blockDim.x + threadIdx.x; g < ngroups;
         g += gridDim.x * blockDim.x) {
        const int j0 = (g & 127) << 2;        // 128 float4-groups per row
        const int i  = (g >> 7) & (H - 1);
        const int p  = g >> 16;               // 65536 groups per (b,c) plane
        const size_t plane = (size_t)p * (H * W);
        const float* ob = out_p + plane;
        const float* lb = lab_p + plane;

        float dm[6], dc[6], dp_[6];           // d at cols j0-1 .. j0+4

        // row i (needed for gx)
        {
            const float* o = ob + i * W + j0;
            const float* l = lb + i * W + j0;
            float4 oc = ld4(o), lc = ld4(l);
            dc[1] = oc.x - lc.x; dc[2] = oc.y - lc.y;
            dc[3] = oc.z - lc.z; dc[4] = oc.w - lc.w;
            dc[0] = (j0 > 0)     ? (o[-1] - l[-1]) : 0.f;
            dc[5] = (j0 + 4 < W) ? (o[4]  - l[4])  : 0.f;
        }
        // row i-1
        if (i > 0) {
            const float* o = ob + (i - 1) * W + j0;
            const float* l = lb + (i - 1) * W + j0;
            float4 oc = ld4(o), lc = ld4(l);
            dm[1] = oc.x - lc.x; dm[2] = oc.y - lc.y;
            dm[3] = oc.z - lc.z; dm[4] = oc.w - lc.w;
            dm[0] = (j0 > 0)     ? (o[-1] - l[-1]) : 0.f;
            dm[5] = (j0 + 4 < W) ? (o[4]  - l[4])  : 0.f;
        } else {
            #pragma unroll
            for (int k = 0; k < 6; ++k) dm[k] = 0.f;
        }
        // row i+1
        if (i + 1 < H) {
            const float* o = ob + (i + 1) * W + j0;
            const float* l = lb + (i + 1) * W + j0;
            float4 oc = ld4(o), lc = ld4(l);
            dp_[1] = oc.x - lc.x; dp_[2] = oc.y - lc.y;
            dp_[3] = oc.z - lc.z; dp_[4] = oc.w - lc.w;
            dp_[0] = (j0 > 0)     ? (o[-1] - l[-1]) : 0.f;
            dp_[5] = (j0 + 4 < W) ? (o[4]  - l[4])  : 0.f;
        } else {
            #pragma unroll
            for (int k = 0; k < 6; ++k) dp_[k] = 0.f;
        }

        #pragma unroll
        for (int k = 0; k < 4; ++k) {
            float gy = dm[k + 1] - dp_[k + 1];   // x[i-1,j]   - x[i+1,j]
            float gx = dc[k]     - dc[k + 2];    // x[i,j-1]   - x[i,j+1]
            float gD = dm[k]     - dp_[k + 2];   // x[i-1,j-1] - x[i+1,j+1]
            float gd = dm[k + 2] - dp_[k];       // x[i-1,j+1] - x[i+1,j-1]
            acc += fabsf(gy) + fabsf(gx) + fabsf(gD) + fabsf(gd);
        }
    }

    // 64-lane wave reduce
    #pragma unroll
    for (int off = 32; off > 0; off >>= 1)
        acc += __shfl_down(acc, off, 64);

    __shared__ float smem[NTHREADS / 64];
    const int lane = threadIdx.x & 63;
    const int wid  = threadIdx.x >> 6;
    if (lane == 0) smem[wid] = acc;
    __syncthreads();
    if (threadIdx.x == 0) {
        float s = 0.f;
        #pragma unroll
        for (int w = 0; w < NTHREADS / 64; ++w) s += smem[w];
        partial[blockIdx.x] = s;
    }
}

__global__ __launch_bounds__(256) void struct_loss_final(
        const float* __restrict__ partial, float* __restrict__ out,
        int nparts, double inv_count) {
    double acc = 0.0;
    for (int i = threadIdx.x; i < nparts; i += blockDim.x)
        acc += (double)partial[i];
    #pragma unroll
    for (int off = 32; off > 0; off >>= 1)
        acc += __shfl_down(acc, off, 64);
    __shared__ double smem[4];
    const int lane = threadIdx.x & 63;
    const int wid  = threadIdx.x >> 6;
    if (lane == 0) smem[wid] = acc;
    __syncthreads();
    if (threadIdx.x == 0) {
        double s = smem[0] + smem[1] + smem[2] + smem[3];
        out[0] = (float)sqrt(s * inv_count + 1e-16);
    }
}

extern "C" void kernel_launch(void* const* d_in, const int* in_sizes, int n_in,
                              void* d_out, int out_size, void* d_ws, size_t ws_size,
                              hipStream_t stream) {
    const float* outputs = (const float*)d_in[0];
    const float* labels  = (const float*)d_in[1];
    float* out = (float*)d_out;
    float* partials = (float*)d_ws;   // NBLOCKS floats

    const int ngroups = (16 * 6 * 512 * 512) / 4;          // 6,291,456
    const double inv_count = 1.0 / (16.0 * 24.0 * 512.0 * 512.0); // mean over B*4C*H*W

    struct_loss_partial<<<NBLOCKS, NTHREADS, 0, stream>>>(outputs, labels,
                                                          partials, ngroups);
    struct_loss_final<<<1, 256, 0, stream>>>(partials, out, NBLOCKS, inv_count);
}

// Round 2
// 45.464 us; speedup vs baseline: 2.0862x; 2.0862x over previous
//
#include <hip/hip_runtime.h>
#include <math.h>

// StructLoss: sqrt(mean(|grads4(outputs - labels)|) + 1e-16)
// grads4 is linear -> compute on d = outputs - labels directly.
// [B=16, C=6, H=512, W=512] fp32; mean over B*4C*H*W.
//
// Layout: one 64-lane wave owns a full 512-wide row (lane l -> cols 8l..8l+7),
// walks an 8-row vertical strip with a rolling 3-row register window of d.
// Column neighbors via __shfl; image edges are zero-pad (lane 0/63).

#define NTHREADS 256
#define STRIP 8
#define WV 512          // image width
#define HT 512          // image height
#define PLANES 96       // B*C
#define STRIPS_PER_PLANE (HT / STRIP)                 // 64
#define TOTAL_WAVES (PLANES * STRIPS_PER_PLANE)       // 6144
#define NBLOCKS (TOTAL_WAVES / (NTHREADS / 64))       // 1536

struct Row {
    float d[8];
    float eL, eR;   // column j0-1 and j0+8 (neighbor-lane values / zero pad)
};

__device__ __forceinline__ Row load_row(const float* __restrict__ ob,
                                         const float* __restrict__ lb,
                                         int r, int lane) {
    Row row;
    const size_t off = (size_t)r * WV;
    const float4 o0 = *reinterpret_cast<const float4*>(ob + off);
    const float4 o1 = *reinterpret_cast<const float4*>(ob + off + 4);
    const float4 l0 = *reinterpret_cast<const float4*>(lb + off);
    const float4 l1 = *reinterpret_cast<const float4*>(lb + off + 4);
    row.d[0] = o0.x - l0.x; row.d[1] = o0.y - l0.y;
    row.d[2] = o0.z - l0.z; row.d[3] = o0.w - l0.w;
    row.d[4] = o1.x - l1.x; row.d[5] = o1.y - l1.y;
    row.d[6] = o1.z - l1.z; row.d[7] = o1.w - l1.w;
    const float up = __shfl_up(row.d[7], 1, 64);
    const float dn = __shfl_down(row.d[0], 1, 64);
    row.eL = (lane == 0) ? 0.f : up;      // col 8l-1 ; lane 0 -> image pad
    row.eR = (lane == 63) ? 0.f : dn;     // col 8l+8 ; lane 63 -> image pad
    return row;
}

__device__ __forceinline__ Row zero_row() {
    Row row;
    #pragma unroll
    for (int k = 0; k < 8; ++k) row.d[k] = 0.f;
    row.eL = 0.f; row.eR = 0.f;
    return row;
}

__global__ __launch_bounds__(NTHREADS) void struct_loss_partial(
        const float* __restrict__ out_p, const float* __restrict__ lab_p,
        float* __restrict__ partial) {
    const int gwave = (blockIdx.x * NTHREADS + threadIdx.x) >> 6;  // 0..6143
    const int lane  = threadIdx.x & 63;
    const int plane = gwave >> 6;                 // /STRIPS_PER_PLANE
    const int row0  = (gwave & 63) * STRIP;

    const size_t base = (size_t)plane * (HT * WV) + lane * 8;
    const float* ob = out_p + base;
    const float* lb = lab_p + base;

    float acc = 0.f;

    Row rp = (row0 > 0) ? load_row(ob, lb, row0 - 1, lane) : zero_row();
    Row rc = load_row(ob, lb, row0, lane);

    #pragma unroll
    for (int rr = 0; rr < STRIP; ++rr) {
        const int r = row0 + rr;
        Row rn = (r + 1 < HT) ? load_row(ob, lb, r + 1, lane) : zero_row();

        #pragma unroll
        for (int k = 0; k < 8; ++k) {
            const float cL = (k > 0) ? rc.d[k - 1] : rc.eL;
            const float cR = (k < 7) ? rc.d[k + 1] : rc.eR;
            const float pL = (k > 0) ? rp.d[k - 1] : rp.eL;
            const float pR = (k < 7) ? rp.d[k + 1] : rp.eR;
            const float nL = (k > 0) ? rn.d[k - 1] : rn.eL;
            const float nR = (k < 7) ? rn.d[k + 1] : rn.eR;

            const float gy = rp.d[k] - rn.d[k];   // x[i-1,j]   - x[i+1,j]
            const float gx = cL - cR;             // x[i,j-1]   - x[i,j+1]
            const float gD = pL - nR;             // x[i-1,j-1] - x[i+1,j+1]
            const float gd = pR - nL;             // x[i-1,j+1] - x[i+1,j-1]
            acc += fabsf(gy) + fabsf(gx) + fabsf(gD) + fabsf(gd);
        }
        rp = rc;
        rc = rn;
    }

    // 64-lane wave reduce
    #pragma unroll
    for (int off = 32; off > 0; off >>= 1)
        acc += __shfl_down(acc, off, 64);

    __shared__ float smem[NTHREADS / 64];
    const int wid = threadIdx.x >> 6;
    if (lane == 0) smem[wid] = acc;
    __syncthreads();
    if (threadIdx.x == 0) {
        float s = 0.f;
        #pragma unroll
        for (int w = 0; w < NTHREADS / 64; ++w) s += smem[w];
        partial[blockIdx.x] = s;
    }
}

__global__ __launch_bounds__(256) void struct_loss_final(
        const float* __restrict__ partial, float* __restrict__ out,
        int nparts, double inv_count) {
    double acc = 0.0;
    for (int i = threadIdx.x; i < nparts; i += blockDim.x)
        acc += (double)partial[i];
    #pragma unroll
    for (int off = 32; off > 0; off >>= 1)
        acc += __shfl_down(acc, off, 64);
    __shared__ double smem[4];
    const int lane = threadIdx.x & 63;
    const int wid  = threadIdx.x >> 6;
    if (lane == 0) smem[wid] = acc;
    __syncthreads();
    if (threadIdx.x == 0) {
        double s = smem[0] + smem[1] + smem[2] + smem[3];
        out[0] = (float)sqrt(s * inv_count + 1e-16);
    }
}

extern "C" void kernel_launch(void* const* d_in, const int* in_sizes, int n_in,
                              void* d_out, int out_size, void* d_ws, size_t ws_size,
                              hipStream_t stream) {
    const float* outputs = (const float*)d_in[0];
    const float* labels  = (const float*)d_in[1];
    float* out = (float*)d_out;
    float* partials = (float*)d_ws;   // NBLOCKS floats

    const double inv_count = 1.0 / (16.0 * 24.0 * 512.0 * 512.0);

    struct_loss_partial<<<NBLOCKS, NTHREADS, 0, stream>>>(outputs, labels, partials);
    struct_loss_final<<<1, 256, 0, stream>>>(partials, out, NBLOCKS, inv_count);
}